// Round 7
// baseline (87.548 us; speedup 1.0000x reference)
//
#include <hip/hip_runtime.h>

typedef __bf16 bf16_t;
typedef __bf16 bf16x2 __attribute__((ext_vector_type(2)));
typedef __bf16 bf16x4 __attribute__((ext_vector_type(4)));
typedef __bf16 bf16x8 __attribute__((ext_vector_type(8)));
typedef float  f32x4  __attribute__((ext_vector_type(4)));
typedef float  f32x4u __attribute__((ext_vector_type(4), aligned(4)));
typedef unsigned int u32;

#define MFMA16(a, b, c) __builtin_amdgcn_mfma_f32_16x16x32_bf16((a), (b), (c), 0, 0, 0)

// ---------------- LDS: att region ONLY, 17408 B ----------------
// [64][136] bf16, row stride 272 B (natural +16B/row stagger -> 2-way = free).
// x never touches LDS (fragments loaded straight to registers, r6 lesson:
// staging was pure critical path). ONE barrier in the whole kernel.
#define ROWB 272

// Fragment conventions for v_mfma_f32_16x16x32_bf16, D = A*B (verified r0-r6):
//  A (MxK): lane holds A[c0][8g+i], i=0..7
//  B (KxN): lane holds B[8g+i][c0]
//  D (MxN): lane reg r holds D[4g+r][c0]

union W8 { u32 u[4]; bf16x8 v; };

__device__ __forceinline__ u32 pack2(float a, float b) {
    union { bf16x2 h; u32 u; } c;
    c.h[0] = (bf16_t)a; c.h[1] = (bf16_t)b;
    return c.u;
}

__device__ __forceinline__ void st4(char* base, int row, int byteoff, bf16x4 v) {
    *(bf16x4*)(base + row * ROWB + byteoff) = v;
}
__device__ __forceinline__ bf16x8 ld8(const char* base, int row, int byteoff) {
    return *(const bf16x8*)(base + row * ROWB + byteoff);
}

// D-layout -> A/B-frag redistribution within each 4-lane c0-column.
// (algebra verified r3-r6)
__device__ __forceinline__ bf16x8 redist4(u32 w0, u32 w1, u32 w2, u32 w3,
                                          bool gl, bool gh) {
    u32 wd[4] = {w0, w1, w2, w3};
    u32 X[4], Y[4], Z[4];
    #pragma unroll
    for (int j = 0; j < 4; ++j) X[j] = __shfl_xor(wd[j], 16);
    #pragma unroll
    for (int j = 0; j < 4; ++j) Y[j] = __shfl_xor(wd[j], 32);
    #pragma unroll
    for (int j = 0; j < 4; ++j) Z[j] = __shfl_xor(X[j], 32);
    W8 u;
    #pragma unroll
    for (int t = 0; t < 4; ++t) {
        int j0 = t & 1;
        int j1 = j0 + 2;
        u32 lo, hi;
        if (t < 2) { lo = gl ? Z[j0] : wd[j0]; hi = gl ? X[j1] : Y[j1]; }
        else       { lo = gl ? Y[j0] : X[j0];  hi = gl ? wd[j1] : Z[j1]; }
        u.u[t] = gh ? hi : lo;
    }
    return u.v;
}

__global__ void wconv_kernel(const float* __restrict__ qw, const float* __restrict__ pw,
                             bf16_t* __restrict__ o) {
    int i = (blockIdx.x * 256 + threadIdx.x) * 4;   // 64*256*4 = 65536
    const float* src = (i < 49152) ? (qw + i) : (pw + (i - 49152));
    float4 f = *(const float4*)src;
    bf16x4 h;
    h[0] = (bf16_t)f.x; h[1] = (bf16_t)f.y; h[2] = (bf16_t)f.z; h[3] = (bf16_t)f.w;
    *(bf16x4*)(o + i) = h;
}

template<int USEB>
__device__ __forceinline__ bf16x8 ldw(const float* __restrict__ wf,
                                      const bf16_t* __restrict__ wb, int idx) {
    if constexpr (USEB) {
        return *(const bf16x8*)(wb + idx);
    } else {
        float4 f0 = *(const float4*)(wf + idx);
        float4 f1 = *(const float4*)(wf + idx + 4);
        bf16x8 r;
        r[0] = (bf16_t)f0.x; r[1] = (bf16_t)f0.y; r[2] = (bf16_t)f0.z; r[3] = (bf16_t)f0.w;
        r[4] = (bf16_t)f1.x; r[5] = (bf16_t)f1.y; r[6] = (bf16_t)f1.z; r[7] = (bf16_t)f1.w;
        return r;
    }
}

// One 32-row slab of W @ x^T (rows rowbase..+31), xf from REGISTERS.
// out[t] = lane holds M[16t+c0][dh 8g+i] (A-frag for row-tile t).
template<int USEB>
__device__ __forceinline__ void qk_pass(
    const bf16x8 xf[4][4], const float* __restrict__ wf, const bf16_t* __restrict__ wb,
    int rowbase, const float* __restrict__ biasp, float scale,
    int g, int c0, bool gl, bool gh, bf16x8 out[4])
{
    f32x4 acc[2][4];
    #pragma unroll
    for (int d = 0; d < 2; ++d)
        #pragma unroll
        for (int mt = 0; mt < 4; ++mt) acc[d][mt] = {0.f, 0.f, 0.f, 0.f};
    #pragma unroll
    for (int ks = 0; ks < 4; ++ks) {
        bf16x8 w0 = ldw<USEB>(wf, wb, (rowbase + c0) * 128 + 32 * ks + 8 * g);
        bf16x8 w1 = ldw<USEB>(wf, wb, (rowbase + 16 + c0) * 128 + 32 * ks + 8 * g);
        #pragma unroll
        for (int mt = 0; mt < 4; ++mt) {
            acc[0][mt] = MFMA16(w0, xf[mt][ks], acc[0][mt]);   // D[dh 0-15][tok]
            acc[1][mt] = MFMA16(w1, xf[mt][ks], acc[1][mt]);   // D[dh 16-31][tok]
        }
    }
    float4 b0 = *(const float4*)(biasp + rowbase + 4 * g);
    float4 b1 = *(const float4*)(biasp + rowbase + 16 + 4 * g);
    #pragma unroll
    for (int t = 0; t < 4; ++t) {
        out[t] = redist4(
            pack2((acc[0][t][0] + b0.x) * scale, (acc[0][t][1] + b0.y) * scale),
            pack2((acc[0][t][2] + b0.z) * scale, (acc[0][t][3] + b0.w) * scale),
            pack2((acc[1][t][0] + b1.x) * scale, (acc[1][t][1] + b1.y) * scale),
            pack2((acc[1][t][2] + b1.z) * scale, (acc[1][t][3] + b1.w) * scale),
            gl, gh);
    }
}

template<int USEB>
__global__ __launch_bounds__(256, 3) void winattn_kernel(
    const float* __restrict__ xg, const float* __restrict__ maskg,
    const float* __restrict__ qwg, const float* __restrict__ qbg,
    const float* __restrict__ pwg, const float* __restrict__ pbg,
    const bf16_t* __restrict__ wqb, const bf16_t* __restrict__ wpb,
    const int nW, float* __restrict__ outg)
{
    __shared__ char as_[17408];   // att only

    const int b    = blockIdx.x;
    const int tid  = threadIdx.x;
    const int w    = tid >> 6;       // wave 0..3 == head
    const int lane = tid & 63;
    const int g    = lane >> 4;
    const int c0   = lane & 15;
    const bool gl  = (g & 1) != 0, gh = (g & 2) != 0;
    const int h    = w;

    // ---- x fragments straight from global -> registers (cvt once) ----
    // Per lane: contiguous 32B row segment x[row][32ks+8g .. +8). Rows >48
    // clamp to 48 (finite duplicates; K tile-3 masked, P[kv>=49]==0, q>=49
    // never stored) — avoids OOB on the last block.
    bf16x8 xf[4][4];
    {
        const float* xb = xg + (long)b * 6272;
        #pragma unroll
        for (int mt = 0; mt < 4; ++mt) {
            int row = 16 * mt + c0;
            row = row > 48 ? 48 : row;
            const float* rp = xb + row * 128 + 8 * g;
            #pragma unroll
            for (int ks = 0; ks < 4; ++ks) {
                float4 f0 = *(const float4*)(rp + 32 * ks);
                float4 f1 = *(const float4*)(rp + 32 * ks + 4);
                bf16x8 r;
                r[0] = (bf16_t)f0.x; r[1] = (bf16_t)f0.y; r[2] = (bf16_t)f0.z; r[3] = (bf16_t)f0.w;
                r[4] = (bf16_t)f1.x; r[5] = (bf16_t)f1.y; r[6] = (bf16_t)f1.z; r[7] = (bf16_t)f1.w;
                xf[mt][ks] = r;
            }
        }
    }

    // ---- QKV, all in registers (one head per wave), NO barriers ----
    const float qs = 0.17677669529663687f;   // 32^-0.5
    bf16x8 qfr[4], ka[4];
    qk_pass<USEB>(xf, qwg, wqb, 32 * h,       qbg, qs,  g, c0, gl, gh, qfr);
    qk_pass<USEB>(xf, qwg, wqb, 128 + 32 * h, qbg, 1.f, g, c0, gl, gh, ka);

    // V pass: D[tok][dh], redist merges tok-tiles -> va[fi][kt] = vT[16fi+c0][32kt+8g+i]
    bf16x8 va[2][2];
    {
        const int rb = 256 + 32 * h;
        f32x4 acc[4][2];
        #pragma unroll
        for (int mt = 0; mt < 4; ++mt)
            #pragma unroll
            for (int d = 0; d < 2; ++d) acc[mt][d] = {0.f, 0.f, 0.f, 0.f};
        #pragma unroll
        for (int ks = 0; ks < 4; ++ks) {
            bf16x8 w0 = ldw<USEB>(qwg, wqb, (rb + c0) * 128 + 32 * ks + 8 * g);
            bf16x8 w1 = ldw<USEB>(qwg, wqb, (rb + 16 + c0) * 128 + 32 * ks + 8 * g);
            #pragma unroll
            for (int mt = 0; mt < 4; ++mt) {
                acc[mt][0] = MFMA16(xf[mt][ks], w0, acc[mt][0]);   // D[tok][dh 0-15]
                acc[mt][1] = MFMA16(xf[mt][ks], w1, acc[mt][1]);   // D[tok][dh 16-31]
            }
        }
        float vb0 = qbg[rb + c0];
        float vb1 = qbg[rb + 16 + c0];
        #pragma unroll
        for (int kt = 0; kt < 2; ++kt) {
            va[0][kt] = redist4(
                pack2(acc[2 * kt][0][0] + vb0, acc[2 * kt][0][1] + vb0),
                pack2(acc[2 * kt][0][2] + vb0, acc[2 * kt][0][3] + vb0),
                pack2(acc[2 * kt + 1][0][0] + vb0, acc[2 * kt + 1][0][1] + vb0),
                pack2(acc[2 * kt + 1][0][2] + vb0, acc[2 * kt + 1][0][3] + vb0),
                gl, gh);
            va[1][kt] = redist4(
                pack2(acc[2 * kt][1][0] + vb1, acc[2 * kt][1][1] + vb1),
                pack2(acc[2 * kt][1][2] + vb1, acc[2 * kt][1][3] + vb1),
                pack2(acc[2 * kt + 1][1][0] + vb1, acc[2 * kt + 1][1][1] + vb1),
                pack2(acc[2 * kt + 1][1][2] + vb1, acc[2 * kt + 1][1][3] + vb1),
                gl, gh);
        }
    }

    // ---- attention per 16-q-tile: S^T -> softmax -> redist P -> PV -> att ----
    const float* mrow = maskg + (long)(b % nW) * 2401;
    #pragma unroll
    for (int nt = 0; nt < 4; ++nt) {
        f32x4 s[4];
        #pragma unroll
        for (int kt = 0; kt < 4; ++kt) s[kt] = {0.f, 0.f, 0.f, 0.f};
        #pragma unroll
        for (int kt = 0; kt < 4; ++kt)
            s[kt] = MFMA16(ka[kt], qfr[nt], s[kt]);   // D[kv][q]: kv=16kt+4g+r, q=16nt+c0

        // fold mask in place (kv tile 3: only kv=48 valid, g==0 r==0)
        {
            int q  = 16 * nt + c0;
            int qm = q < 49 ? q : 48;
            const float* mr = mrow + qm * 49;
            f32x4u m0 = *(const f32x4u*)(mr + 4 * g);
            f32x4u m1 = *(const f32x4u*)(mr + 16 + 4 * g);
            f32x4u m2 = *(const f32x4u*)(mr + 32 + 4 * g);
            float m48 = mr[48];
            #pragma unroll
            for (int r = 0; r < 4; ++r) {
                s[0][r] += m0[r]; s[1][r] += m1[r]; s[2][r] += m2[r];
            }
            s[3][0] = (g == 0) ? s[3][0] + m48 : -1e30f;
            s[3][1] = -1e30f; s[3][2] = -1e30f; s[3][3] = -1e30f;
        }

        float mx = -1e30f;
        #pragma unroll
        for (int kt = 0; kt < 4; ++kt)
            #pragma unroll
            for (int r = 0; r < 4; ++r) mx = fmaxf(mx, s[kt][r]);
        mx = fmaxf(mx, __shfl_xor(mx, 16));
        mx = fmaxf(mx, __shfl_xor(mx, 32));

        float sum = 0.f;
        u32 wd[8];
        #pragma unroll
        for (int kt = 0; kt < 4; ++kt) {
            float e0 = __expf(s[kt][0] - mx), e1 = __expf(s[kt][1] - mx);
            float e2 = __expf(s[kt][2] - mx), e3 = __expf(s[kt][3] - mx);
            sum += (e0 + e1) + (e2 + e3);
            wd[2 * kt]     = pack2(e0, e1);
            wd[2 * kt + 1] = pack2(e2, e3);
        }
        sum += __shfl_xor(sum, 16);
        sum += __shfl_xor(sum, 32);
        float inv = 1.f / sum;   // uniform within the 4-lane c0-column

        bf16x8 pa0 = redist4(wd[0], wd[1], wd[2], wd[3], gl, gh);
        bf16x8 pa1 = redist4(wd[4], wd[5], wd[6], wd[7], gl, gh);

        f32x4 oo[2];
        oo[0] = {0.f, 0.f, 0.f, 0.f}; oo[1] = {0.f, 0.f, 0.f, 0.f};
        oo[0] = MFMA16(va[0][0], pa0, oo[0]);
        oo[0] = MFMA16(va[0][1], pa1, oo[0]);   // D[dh 0-15][q]
        oo[1] = MFMA16(va[1][0], pa0, oo[1]);
        oo[1] = MFMA16(va[1][1], pa1, oo[1]);   // D[dh 16-31][q]

        int q = 16 * nt + c0;
        #pragma unroll
        for (int dt = 0; dt < 2; ++dt) {
            bf16x4 t;
            t[0] = (bf16_t)(oo[dt][0] * inv); t[1] = (bf16_t)(oo[dt][1] * inv);
            t[2] = (bf16_t)(oo[dt][2] * inv); t[3] = (bf16_t)(oo[dt][3] * inv);
            st4(as_, q, (32 * h + 16 * dt + 4 * g) * 2, t);   // att[q][c]
        }
    }

    // prefetch proj weights + bias so they're in flight across the barrier
    bf16x8 pwf[4][2];
    #pragma unroll
    for (int ks = 0; ks < 4; ++ks) {
        pwf[ks][0] = ldw<USEB>(pwg, wpb, (32 * w + c0) * 128 + 32 * ks + 8 * g);
        pwf[ks][1] = ldw<USEB>(pwg, wpb, (32 * w + 16 + c0) * 128 + 32 * ks + 8 * g);
    }
    float4 pb0 = *(const float4*)(pbg + 32 * w + 4 * g);
    float4 pb1 = *(const float4*)(pbg + 32 * w + 16 + 4 * g);
    __syncthreads();   // THE barrier: att complete

    // ---- proj GEMM: D[col][tok] = Wp*att^T; wave owns cols 32w..32w+31 ----
    {
        f32x4 acc[2][4];
        #pragma unroll
        for (int nt = 0; nt < 2; ++nt)
            #pragma unroll
            for (int mt = 0; mt < 4; ++mt) acc[nt][mt] = {0.f, 0.f, 0.f, 0.f};
        #pragma unroll
        for (int ks = 0; ks < 4; ++ks) {
            #pragma unroll
            for (int mt = 0; mt < 4; ++mt) {
                bf16x8 af = ld8(as_, 16 * mt + c0, (32 * ks + 8 * g) * 2);
                acc[0][mt] = MFMA16(pwf[ks][0], af, acc[0][mt]);
                acc[1][mt] = MFMA16(pwf[ks][1], af, acc[1][mt]);
            }
        }
        float* ob = outg + (long)b * 6272;
        #pragma unroll
        for (int nt = 0; nt < 2; ++nt) {
            float4 pb = nt ? pb1 : pb0;
            #pragma unroll
            for (int mt = 0; mt < 4; ++mt) {
                int tok = 16 * mt + c0;
                if (tok < 49) {
                    float4 t;
                    t.x = acc[nt][mt][0] + pb.x;
                    t.y = acc[nt][mt][1] + pb.y;
                    t.z = acc[nt][mt][2] + pb.z;
                    t.w = acc[nt][mt][3] + pb.w;
                    *(float4*)(ob + tok * 128 + 32 * w + 16 * nt + 4 * g) = t;
                }
            }
        }
    }
}

extern "C" void kernel_launch(void* const* d_in, const int* in_sizes, int n_in,
                              void* d_out, int out_size, void* d_ws, size_t ws_size,
                              hipStream_t stream) {
    const float* xg  = (const float*)d_in[0];
    const float* mg  = (const float*)d_in[1];
    const float* qwg = (const float*)d_in[2];
    const float* qbg = (const float*)d_in[3];
    const float* pwg = (const float*)d_in[4];
    const float* pbg = (const float*)d_in[5];
    float* outg = (float*)d_out;

    const int B  = in_sizes[0] / (49 * 128);   // 2048
    const int nW = in_sizes[1] / (49 * 49);    // 64

    int use_wbf = (d_ws != nullptr && ws_size >= 131072) ? 1 : 0;
    bf16_t* wqb = (bf16_t*)d_ws;
    bf16_t* wpb = use_wbf ? (wqb + 49152) : nullptr;

    if (use_wbf) {
        wconv_kernel<<<64, 256, 0, stream>>>(qwg, pwg, wqb);
        winattn_kernel<1><<<B, 256, 0, stream>>>(
            xg, mg, qwg, qbg, pwg, pbg, wqb, wpb, nW, outg);
    } else {
        winattn_kernel<0><<<B, 256, 0, stream>>>(
            xg, mg, qwg, qbg, pwg, pbg, nullptr, nullptr, nW, outg);
    }
}